// Round 1
// baseline (2980.024 us; speedup 1.0000x reference)
//
#include <hip/hip_runtime.h>
#include <math.h>

#define HID 51
#define TMAIN 1024
#define FUT 64
#define TT (TMAIN + FUT)

__device__ __forceinline__ float fast_sigmoid(float x) {
  return 1.0f / (1.0f + __expf(-x));
}
__device__ __forceinline__ float fast_tanh(float x) {
  // stable both directions: x>>0 -> 1, x<<0 -> -1
  return 1.0f - 2.0f / (__expf(2.0f * x) + 1.0f);
}

// acc[g] += sum_k w[g][k] * hbuf[k], k = 0..50. hbuf is 16B-aligned LDS.
__device__ __forceinline__ void dot_rows(const float* hbuf,
                                         const float (&w)[4][HID],
                                         float (&acc)[4]) {
  const float4* h4 = reinterpret_cast<const float4*>(hbuf);
#pragma unroll
  for (int q = 0; q < 12; ++q) {
    float4 hv = h4[q];
#pragma unroll
    for (int g = 0; g < 4; ++g) {
      acc[g] = fmaf(hv.x, w[g][4 * q + 0], acc[g]);
      acc[g] = fmaf(hv.y, w[g][4 * q + 1], acc[g]);
      acc[g] = fmaf(hv.z, w[g][4 * q + 2], acc[g]);
      acc[g] = fmaf(hv.w, w[g][4 * q + 3], acc[g]);
    }
  }
  float h48 = hbuf[48], h49 = hbuf[49], h50 = hbuf[50];
#pragma unroll
  for (int g = 0; g < 4; ++g) {
    acc[g] = fmaf(h48, w[g][48], acc[g]);
    acc[g] = fmaf(h49, w[g][49], acc[g]);
    acc[g] = fmaf(h50, w[g][50], acc[g]);
  }
}

// One block = one batch element. 3 waves:
//   wave 0: W_hh1 rows (layer-1 recurrent) + layer-1 cell (c1 in regs)
//   wave 1: W_hh2 rows (layer-2 recurrent partial)
//   wave 2: W_ih2 rows (layer-2 input) + layer-2 cell (c2 in regs) + linear out
// Lane j (j<51) of each wave holds the 4 gate rows (i,f,g,o) of hidden unit j
// in 204 VGPRs. Weights never touch memory after the preamble.
__global__ __launch_bounds__(192, 2)
void lstm2_persistent(const float* __restrict__ input,
                      const float* __restrict__ Wi1,
                      const float* __restrict__ Wh1,
                      const float* __restrict__ bi1,
                      const float* __restrict__ bh1,
                      const float* __restrict__ Wi2,
                      const float* __restrict__ Wh2,
                      const float* __restrict__ bi2,
                      const float* __restrict__ bh2,
                      const float* __restrict__ Wlin,
                      const float* __restrict__ blin,
                      float* __restrict__ out) {
  __shared__ __align__(16) float lds_x[TMAIN];
  __shared__ __align__(16) float lds_h1[64];
  __shared__ __align__(16) float lds_h2[64];
  __shared__ __align__(16) float lds_p2[4][64];
  __shared__ float lds_fb[1];

  const int b = blockIdx.x;
  const int tid = threadIdx.x;
  const int wid = tid >> 6;
  const int lane = tid & 63;
  const bool act = lane < HID;
  const int j = act ? lane : 0;  // clamped row index for inactive lanes

  // Stage this sequence's input row into LDS (coalesced).
  for (int i = tid; i < TMAIN; i += 192) lds_x[i] = input[b * TMAIN + i];
  if (tid < 64) {
    lds_h1[tid] = 0.0f;
    lds_h2[tid] = 0.0f;
  }

  // ---- Load this wave's weight rows into registers ----
  float w[4][HID];
  float bias[4] = {0.f, 0.f, 0.f, 0.f};
  float wi1g[4] = {0.f, 0.f, 0.f, 0.f};
  float wlin_j = 0.0f;
  float c_state = 0.0f;

  const float* Wsel = (wid == 0) ? Wh1 : ((wid == 1) ? Wh2 : Wi2);
#pragma unroll
  for (int g = 0; g < 4; ++g) {
    const float* row = Wsel + (g * HID + j) * HID;
#pragma unroll
    for (int k = 0; k < HID; ++k) w[g][k] = row[k];
  }
  if (wid == 0) {
#pragma unroll
    for (int g = 0; g < 4; ++g) {
      bias[g] = bi1[g * HID + j] + bh1[g * HID + j];
      wi1g[g] = Wi1[g * HID + j];
    }
  } else if (wid == 2) {
#pragma unroll
    for (int g = 0; g < 4; ++g) bias[g] = bi2[g * HID + j] + bh2[g * HID + j];
    wlin_j = Wlin[j];
  }
  const float blin_s = blin[0];

  __syncthreads();

  for (int t = 0; t < TT; ++t) {
    // ---------------- phase 1 ----------------
    if (wid == 0) {
      // layer-1 gates: x*Wi1 + bias + Wh1 @ h1_prev ; then cell update
      float x = (t < TMAIN) ? lds_x[t] : lds_fb[0];
      float acc[4];
#pragma unroll
      for (int g = 0; g < 4; ++g) acc[g] = fmaf(x, wi1g[g], bias[g]);
      dot_rows(lds_h1, w, acc);
      float gi = fast_sigmoid(acc[0]);
      float gf = fast_sigmoid(acc[1]);
      float gg = fast_tanh(acc[2]);
      float go = fast_sigmoid(acc[3]);
      c_state = gf * c_state + gi * gg;
      float h = go * fast_tanh(c_state);
      if (act) lds_h1[lane] = h;  // intra-wave: all reads precede this write
    } else if (wid == 1) {
      // layer-2 recurrent partial: Wh2 @ h2_prev
      float acc[4] = {0.f, 0.f, 0.f, 0.f};
      dot_rows(lds_h2, w, acc);
      if (act) {
#pragma unroll
        for (int g = 0; g < 4; ++g) lds_p2[g][lane] = acc[g];
      }
    }
    __syncthreads();  // h1_new + p2 visible

    // ---------------- phase 2 ----------------
    if (wid == 2) {
      float acc[4];
#pragma unroll
      for (int g = 0; g < 4; ++g) acc[g] = bias[g] + lds_p2[g][j];
      dot_rows(lds_h1, w, acc);  // Wi2 @ h1_new
      float gi = fast_sigmoid(acc[0]);
      float gf = fast_sigmoid(acc[1]);
      float gg = fast_tanh(acc[2]);
      float go = fast_sigmoid(acc[3]);
      c_state = gf * c_state + gi * gg;
      float h = go * fast_tanh(c_state);
      float val = 0.0f;
      if (act) {
        lds_h2[lane] = h;
        val = wlin_j * h;
      }
      // linear head: out = sum_j wlin[j]*h2[j] + blin  (butterfly over 64)
#pragma unroll
      for (int off = 32; off >= 1; off >>= 1) val += __shfl_xor(val, off);
      if (lane == 0) {
        float o = val + blin_s;
        out[b * TT + t] = o;
        lds_fb[0] = o;  // feedback input for the future phase
      }
    }
    __syncthreads();  // h2_new + fb visible for next timestep
  }
}

extern "C" void kernel_launch(void* const* d_in, const int* in_sizes, int n_in,
                              void* d_out, int out_size, void* d_ws,
                              size_t ws_size, hipStream_t stream) {
  const float* input = (const float*)d_in[0];
  const float* Wi1 = (const float*)d_in[1];
  const float* Wh1 = (const float*)d_in[2];
  const float* bi1 = (const float*)d_in[3];
  const float* bh1 = (const float*)d_in[4];
  const float* Wi2 = (const float*)d_in[5];
  const float* Wh2 = (const float*)d_in[6];
  const float* bi2 = (const float*)d_in[7];
  const float* bh2 = (const float*)d_in[8];
  const float* Wlin = (const float*)d_in[9];
  const float* blin = (const float*)d_in[10];
  float* out = (float*)d_out;

  const int B = in_sizes[0] / TMAIN;  // 512
  lstm2_persistent<<<B, 192, 0, stream>>>(input, Wi1, Wh1, bi1, bh1, Wi2, Wh2,
                                          bi2, bh2, Wlin, blin, out);
}